// Round 1
// baseline (596.193 us; speedup 1.0000x reference)
//
#include <hip/hip_runtime.h>

typedef __attribute__((ext_vector_type(8))) short bhalf8;
typedef __attribute__((ext_vector_type(4))) float floatx4;

constexpr int B_ = 2, S_ = 2048, HID_ = 2048, NH_ = 32, NKV_ = 8, HD_ = 64;
constexpr float LAMBDA_INIT_F = 0.35550906759096924f;
constexpr float EPS_ = 1e-6f;

#define DEVINL __device__ __forceinline__

DEVINL float bf2f(unsigned short u) {
    union { unsigned u; float f; } v; v.u = ((unsigned)u) << 16; return v.f;
}
DEVINL unsigned short f2bf(float f) {
    union { float f; unsigned u; } v; v.f = f;
    unsigned u = v.u;
    return (unsigned short)((u + 0x7fffu + ((u >> 16) & 1u)) >> 16);
}

// ---------------- fp32 -> bf16 convert ----------------
__global__ void cvt_f32_bf16(const float* __restrict__ src, unsigned short* __restrict__ dst, int n) {
    int i = (blockIdx.x * 256 + threadIdx.x) * 4;
    if (i < n) {
        float4 v = *(const float4*)(src + i);
        ushort4 o;
        o.x = f2bf(v.x); o.y = f2bf(v.y); o.z = f2bf(v.z); o.w = f2bf(v.w);
        *(ushort4*)(dst + i) = o;
    }
}

// ---------------- lambda scalar ----------------
__global__ void lam_kernel(const float* __restrict__ q1, const float* __restrict__ k1,
                           const float* __restrict__ q2, const float* __restrict__ k2,
                           float* __restrict__ lam) {
    const int l = threadIdx.x;  // 64
    float p1 = q1[l] * k1[l];
    float p2 = q2[l] * k2[l];
    #pragma unroll
    for (int off = 1; off < 64; off <<= 1) {
        p1 += __shfl_xor(p1, off, 64);
        p2 += __shfl_xor(p2, off, 64);
    }
    if (l == 0) *lam = expf(p1) - expf(p2) + LAMBDA_INIT_F;
}

// ---------------- GEMM: C[M][N] = A[M][K] . Bw[N][K]^T  (bf16 in, fp32/bf16 out) ----------------
template <bool OUT_BF16>
__global__ __launch_bounds__(256)
void gemm_bt(const unsigned short* __restrict__ A, const unsigned short* __restrict__ Bw,
             void* __restrict__ Cout, int M, int N, int K) {
    __shared__ __align__(16) unsigned short As[128][40];  // pad 40 -> 80B stride
    __shared__ __align__(16) unsigned short Bs[128][40];
    const int t = threadIdx.x;
    const int w = t >> 6, lane = t & 63, quad = lane >> 4, lid = lane & 15;
    const int wr = (w >> 1) * 64, wc = (w & 1) * 64;
    const long bm = (long)blockIdx.x * 128, bn = (long)blockIdx.y * 128;

    floatx4 acc[4][4];
    #pragma unroll
    for (int i = 0; i < 4; i++)
        #pragma unroll
        for (int j = 0; j < 4; j++) acc[i][j] = (floatx4){0.f, 0.f, 0.f, 0.f};

    const int rS = t >> 1, kS = (t & 1) * 16;
    const unsigned short* Ap = A + (bm + rS) * (long)K + kS;
    const unsigned short* Bp = Bw + (bn + rS) * (long)K + kS;

    for (int kt = 0; kt < K; kt += 32) {
        int4 a0 = *(const int4*)(Ap);
        int4 a1 = *(const int4*)(Ap + 8);
        int4 b0 = *(const int4*)(Bp);
        int4 b1 = *(const int4*)(Bp + 8);
        __syncthreads();  // prev compute done before overwrite
        *(int4*)&As[rS][kS] = a0;
        *(int4*)&As[rS][kS + 8] = a1;
        *(int4*)&Bs[rS][kS] = b0;
        *(int4*)&Bs[rS][kS + 8] = b1;
        __syncthreads();
        bhalf8 af[4], bf[4];
        #pragma unroll
        for (int i = 0; i < 4; i++) af[i] = *(const bhalf8*)&As[wr + i * 16 + lid][quad * 8];
        #pragma unroll
        for (int j = 0; j < 4; j++) bf[j] = *(const bhalf8*)&Bs[wc + j * 16 + lid][quad * 8];
        #pragma unroll
        for (int i = 0; i < 4; i++)
            #pragma unroll
            for (int j = 0; j < 4; j++)
                acc[i][j] = __builtin_amdgcn_mfma_f32_16x16x32_bf16(af[i], bf[j], acc[i][j], 0, 0, 0);
        Ap += 32;
        Bp += 32;
    }

    #pragma unroll
    for (int i = 0; i < 4; i++) {
        #pragma unroll
        for (int j = 0; j < 4; j++) {
            const long row = bm + wr + i * 16 + quad * 4;
            const long col = bn + wc + j * 16 + lid;
            #pragma unroll
            for (int r = 0; r < 4; r++) {
                float v = acc[i][j][r];
                if (OUT_BF16)
                    ((unsigned short*)Cout)[(row + r) * N + col] = f2bf(v);
                else
                    ((float*)Cout)[(row + r) * N + col] = v;
            }
        }
    }
}

// ---------------- RoPE + split into Q/K/V head-major layouts ----------------
__global__ __launch_bounds__(256)
void rope_split(const unsigned short* __restrict__ qkv, const float* __restrict__ cosb,
                const float* __restrict__ sinb, unsigned short* __restrict__ Qr,
                unsigned short* __restrict__ Kr, unsigned short* __restrict__ Vr) {
    const int r = blockIdx.x;  // b*S + s
    const int b = r >> 11, s = r & 2047;
    const int t = threadIdx.x;
    const unsigned short* rowp = qkv + (size_t)r * 3072;
    #pragma unroll
    for (int i = 0; i < 8; i++) {
        const int c = t * 8 + i;  // 0..2047 (q)
        const int h = c >> 6, d = c & 63;
        const float x = bf2f(rowp[c]);
        const float oth = bf2f(rowp[(h << 6) + ((d < 32) ? d + 32 : d - 32)]);
        const float rot = (d < 32) ? -oth : oth;
        const float y = x * cosb[(size_t)r * 64 + d] + rot * sinb[(size_t)r * 64 + d];
        Qr[((size_t)(b * NH_ + h) * S_ + s) * HD_ + d] = f2bf(y);
    }
    #pragma unroll
    for (int i = 0; i < 2; i++) {
        const int c = t * 2 + i;  // 0..511 (k / v)
        const int h = c >> 6, d = c & 63;
        const float x = bf2f(rowp[2048 + c]);
        const float oth = bf2f(rowp[2048 + (h << 6) + ((d < 32) ? d + 32 : d - 32)]);
        const float rot = (d < 32) ? -oth : oth;
        const float y = x * cosb[(size_t)r * 64 + d] + rot * sinb[(size_t)r * 64 + d];
        Kr[((size_t)(b * NKV_ + h) * S_ + s) * HD_ + d] = f2bf(y);
        Vr[((size_t)(b * NKV_ + h) * S_ + s) * HD_ + d] = rowp[2560 + c];
    }
}

// ---------------- differential flash attention ----------------
// Block: 256 thr = 4 waves. waves 0,1 -> stream 0 (head j), waves 2,3 -> stream 1 (head j+16).
// Each wave owns 16 q-rows; BM=32 q-rows/block, BN=64 keys/step, V-dim 128 = [v_kv1 | v_kv2].
__global__ __launch_bounds__(256)
void attn_diff(const unsigned short* __restrict__ Qr, const unsigned short* __restrict__ Kr,
               const unsigned short* __restrict__ Vr, const float* __restrict__ lamp,
               unsigned short* __restrict__ attn) {
    union SM {
        struct {
            unsigned short Kt[2][64][72];  // [stream][key][dim]
            unsigned short Vt[128][72];    // [dim][key] (transposed)
            unsigned short Pt[4][16][72];  // per-wave P [row][key]
        } a;
        struct { float Ot[2][32][128]; } o;  // [stream][row][dim]
    };
    __shared__ __align__(16) SM sm;

    const int qt = blockIdx.x, j = blockIdx.y, b = blockIdx.z;
    const int qb = qt * 32;
    const int t = threadIdx.x;
    const int w = t >> 6, lane = t & 63, quad = lane >> 4, lid = lane & 15;
    const int st = w >> 1;
    const int rh = (w & 1) * 16;
    const int kv1 = j >> 2, kv2 = 4 + (j >> 2);
    const int qhead = j + st * 16;

    const unsigned short* qbase = Qr + ((size_t)((b * NH_ + qhead) * S_) + qb + rh + lid) * HD_;
    const bhalf8 qa0 = *(const bhalf8*)(qbase + quad * 8);
    const bhalf8 qa1 = *(const bhalf8*)(qbase + 32 + quad * 8);

    floatx4 acc[8];
    #pragma unroll
    for (int c = 0; c < 8; c++) acc[c] = (floatx4){0.f, 0.f, 0.f, 0.f};
    float m_i[4], l_i[4];
    #pragma unroll
    for (int r = 0; r < 4; r++) { m_i[r] = -3.0e38f; l_i[r] = 0.f; }

    const unsigned short* Kg[2] = { Kr + (size_t)(b * NKV_ + kv1) * S_ * HD_,
                                    Kr + (size_t)(b * NKV_ + kv2) * S_ * HD_ };
    const unsigned short* Vg[2] = { Vr + (size_t)(b * NKV_ + kv1) * S_ * HD_,
                                    Vr + (size_t)(b * NKV_ + kv2) * S_ * HD_ };

    const int nkt = ((qb + 31) >> 6) + 1;
    for (int kt = 0; kt < nkt; kt++) {
        const int k0 = kt * 64;
        __syncthreads();  // prev PV reads done before restage
        {   // stage K tiles (both streams)
            const int ss = t >> 7, key = (t & 127) >> 1, dh = (t & 1) * 32;
            const unsigned short* src = Kg[ss] + (size_t)(k0 + key) * HD_ + dh;
            int4 v0 = *(const int4*)(src);
            int4 v1 = *(const int4*)(src + 8);
            int4 v2 = *(const int4*)(src + 16);
            int4 v3 = *(const int4*)(src + 24);
            *(int4*)&sm.a.Kt[ss][key][dh] = v0;
            *(int4*)&sm.a.Kt[ss][key][dh + 8] = v1;
            *(int4*)&sm.a.Kt[ss][key][dh + 16] = v2;
            *(int4*)&sm.a.Kt[ss][key][dh + 24] = v3;
        }
        {   // stage V transposed: dims 0..63 <- kv1, 64..127 <- kv2
            const int key = t & 63, dg = t >> 6;
            const unsigned short* src = Vg[dg >> 1] + (size_t)(k0 + key) * HD_ + (dg & 1) * 32;
            int4 u[4];
            #pragma unroll
            for (int ii = 0; ii < 4; ii++) u[ii] = *(const int4*)(src + ii * 8);
            const unsigned short* us = (const unsigned short*)u;
            #pragma unroll
            for (int d = 0; d < 32; d++) sm.a.Vt[dg * 32 + d][key] = us[d];
        }
        __syncthreads();

        // QK^T : D[row=q][col=key]
        floatx4 sc[4];
        #pragma unroll
        for (int nt = 0; nt < 4; nt++) {
            bhalf8 kb0 = *(const bhalf8*)&sm.a.Kt[st][nt * 16 + lid][quad * 8];
            bhalf8 kb1 = *(const bhalf8*)&sm.a.Kt[st][nt * 16 + lid][32 + quad * 8];
            floatx4 z = (floatx4){0.f, 0.f, 0.f, 0.f};
            z = __builtin_amdgcn_mfma_f32_16x16x32_bf16(qa0, kb0, z, 0, 0, 0);
            z = __builtin_amdgcn_mfma_f32_16x16x32_bf16(qa1, kb1, z, 0, 0, 0);
            sc[nt] = z;
        }

        // scale + causal mask + row max
        float mx[4] = {-3.0e38f, -3.0e38f, -3.0e38f, -3.0e38f};
        #pragma unroll
        for (int nt = 0; nt < 4; nt++) {
            const int keyg = k0 + nt * 16 + lid;
            #pragma unroll
            for (int r = 0; r < 4; r++) {
                const int rowg = qb + rh + quad * 4 + r;
                float s = sc[nt][r] * 0.125f;
                s = (keyg > rowg) ? -1.0e30f : s;
                sc[nt][r] = s;
                mx[r] = fmaxf(mx[r], s);
            }
        }
        #pragma unroll
        for (int off = 1; off < 16; off <<= 1)
            #pragma unroll
            for (int r = 0; r < 4; r++) mx[r] = fmaxf(mx[r], __shfl_xor(mx[r], off, 64));

        float alpha[4], rs[4];
        #pragma unroll
        for (int r = 0; r < 4; r++) {
            const float mn = fmaxf(m_i[r], mx[r]);
            alpha[r] = __expf(m_i[r] - mn);
            m_i[r] = mn;
            rs[r] = 0.f;
        }
        #pragma unroll
        for (int nt = 0; nt < 4; nt++)
            #pragma unroll
            for (int r = 0; r < 4; r++) {
                const float p = __expf(sc[nt][r] - m_i[r]);
                sc[nt][r] = p;
                rs[r] += p;
            }
        #pragma unroll
        for (int off = 1; off < 16; off <<= 1)
            #pragma unroll
            for (int r = 0; r < 4; r++) rs[r] += __shfl_xor(rs[r], off, 64);
        #pragma unroll
        for (int r = 0; r < 4; r++) l_i[r] = l_i[r] * alpha[r] + rs[r];
        #pragma unroll
        for (int c = 0; c < 8; c++)
            #pragma unroll
            for (int r = 0; r < 4; r++) acc[c][r] *= alpha[r];

        // P: C-layout -> LDS -> A-layout
        #pragma unroll
        for (int nt = 0; nt < 4; nt++)
            #pragma unroll
            for (int r = 0; r < 4; r++)
                sm.a.Pt[w][quad * 4 + r][nt * 16 + lid] = f2bf(sc[nt][r]);
        __syncthreads();

        // PV: acc += P(16x64) . V(64x128)
        #pragma unroll
        for (int kk = 0; kk < 2; kk++) {
            const bhalf8 pa = *(const bhalf8*)&sm.a.Pt[w][lid][kk * 32 + quad * 8];
            #pragma unroll
            for (int c = 0; c < 8; c++) {
                const bhalf8 vb = *(const bhalf8*)&sm.a.Vt[c * 16 + lid][kk * 32 + quad * 8];
                acc[c] = __builtin_amdgcn_mfma_f32_16x16x32_bf16(pa, vb, acc[c], 0, 0, 0);
            }
        }
    }

    __syncthreads();  // done with a-region; overlay Ot
    #pragma unroll
    for (int c = 0; c < 8; c++)
        #pragma unroll
        for (int r = 0; r < 4; r++)
            sm.o.Ot[st][rh + quad * 4 + r][c * 16 + lid] = acc[c][r] / l_i[r];
    __syncthreads();

    // combine streams + RMSNorm + scale + store bf16
    const float lam = *lamp;
    const int row = t >> 3, d0 = (t & 7) * 16;
    float vals[16];
    float ss = 0.f;
    #pragma unroll
    for (int i = 0; i < 16; i++) {
        const float x = sm.o.Ot[0][row][d0 + i] - lam * sm.o.Ot[1][row][d0 + i];
        vals[i] = x;
        ss += x * x;
    }
    ss += __shfl_xor(ss, 1, 64);
    ss += __shfl_xor(ss, 2, 64);
    ss += __shfl_xor(ss, 4, 64);
    const float scale = (1.f - LAMBDA_INIT_F) * rsqrtf(ss * (1.f / 128.f) + EPS_);
    unsigned short* dst = attn + (size_t)(b * S_ + qb + row) * (NH_ * HD_) + j * 128 + d0;
    #pragma unroll
    for (int i = 0; i < 16; i++) dst[i] = f2bf(vals[i] * scale);
}

// ---------------- launcher ----------------
extern "C" void kernel_launch(void* const* d_in, const int* in_sizes, int n_in,
                              void* d_out, int out_size, void* d_ws, size_t ws_size,
                              hipStream_t stream) {
    const float* hs   = (const float*)d_in[0];
    const float* cosb = (const float*)d_in[1];
    const float* sinb = (const float*)d_in[2];
    // d_in[3] = attention_mask: deterministic causal triu(-1e9) -> applied as predicate
    const float* wq   = (const float*)d_in[4];
    const float* wk   = (const float*)d_in[5];
    const float* wv   = (const float*)d_in[6];
    const float* wo   = (const float*)d_in[7];
    const float* lq1  = (const float*)d_in[8];
    const float* lk1  = (const float*)d_in[9];
    const float* lq2  = (const float*)d_in[10];
    const float* lk2  = (const float*)d_in[11];

    unsigned short* p = (unsigned short*)d_ws;
    unsigned short* hs_bf = p;  p += (size_t)4096 * 2048;
    unsigned short* wcat  = p;  p += (size_t)3072 * 2048;   // [wq; wk; wv] rows
    unsigned short* wo_bf = p;  p += (size_t)2048 * 2048;
    unsigned short* qkv   = p;  p += (size_t)4096 * 3072;
    unsigned short* Qr    = p;  p += (size_t)B_ * NH_ * S_ * HD_;
    unsigned short* Kr    = p;  p += (size_t)B_ * NKV_ * S_ * HD_;
    unsigned short* Vr    = p;  p += (size_t)B_ * NKV_ * S_ * HD_;
    unsigned short* attnb = p;  p += (size_t)4096 * 2048;
    float* lam = (float*)p;

    cvt_f32_bf16<<<(4096 * 2048) / 1024, 256, 0, stream>>>(hs, hs_bf, 4096 * 2048);
    cvt_f32_bf16<<<(2048 * 2048) / 1024, 256, 0, stream>>>(wq, wcat, 2048 * 2048);
    cvt_f32_bf16<<<(512 * 2048) / 1024, 256, 0, stream>>>(wk, wcat + (size_t)2048 * 2048, 512 * 2048);
    cvt_f32_bf16<<<(512 * 2048) / 1024, 256, 0, stream>>>(wv, wcat + (size_t)2560 * 2048, 512 * 2048);
    cvt_f32_bf16<<<(2048 * 2048) / 1024, 256, 0, stream>>>(wo, wo_bf, 2048 * 2048);
    lam_kernel<<<1, 64, 0, stream>>>(lq1, lk1, lq2, lk2, lam);

    gemm_bt<true><<<dim3(32, 24), 256, 0, stream>>>(hs_bf, wcat, qkv, 4096, 3072, 2048);
    rope_split<<<4096, 256, 0, stream>>>(qkv, cosb, sinb, Qr, Kr, Vr);
    attn_diff<<<dim3(64, 16, 2), 256, 0, stream>>>(Qr, Kr, Vr, lam, attnb);
    gemm_bt<false><<<dim3(32, 16), 256, 0, stream>>>(attnb, wo_bf, d_out, 4096, 2048, 2048);
}